// Round 2
// baseline (160.575 us; speedup 1.0000x reference)
//
#include <hip/hip_runtime.h>

// ---- LDS halo-tile layout (float elements, odd-ish strides vs 32 banks) ----
#define T0STR 20
#define T1STR 39
#define T2STR 77
#define T0OFF 0
#define T1OFF (18 * T0STR)             // 360
#define T2OFF (T1OFF + 36 * T1STR)     // 1764
#define LDSF  (T2OFF + 76 * T2STR)     // 7616 floats = 30464 B

__global__ __launch_bounds__(256, 4) void fuse_kernel(
    const float* __restrict__ x0, const float* __restrict__ x1,
    const float* __restrict__ x2, const float* __restrict__ W,
    float* __restrict__ out)
{
  __shared__ float lds[LDSF];
  const int tid  = threadIdx.x;
  const int bid  = blockIdx.x;
  const int nb   = bid >> 4;           // image 0..63
  const int ty   = (bid >> 2) & 3;     // tile row 0..3 (16 px each)
  const int tx   = bid & 3;            // tile col 0..3
  const int lane = tid & 63;
  const int wid  = tid >> 6;
  const int pc   = lane & 15;          // pixel col within tile
  const int pr   = wid * 4 + (lane >> 4);  // pixel row within tile

  // ---- stage halo tiles to LDS (f32, zero-padded at borders) ----
  {
    const float* img = x0 + nb * 4096;
    for (int idx = tid; idx < 18 * 19; idx += 256) {
      int r = idx / 19, c = idx - r * 19;
      int gy = ty * 16 - 1 + r, gx = tx * 16 - 1 + c;
      float v = (gy >= 0 && gy < 64 && gx >= 0 && gx < 64) ? img[gy * 64 + gx] : 0.f;
      lds[T0OFF + r * T0STR + c] = v;
    }
  }
  {
    const float* img = x1 + nb * 16384;
    for (int idx = tid; idx < 36 * 38; idx += 256) {
      int r = idx / 38, c = idx - r * 38;
      int gy = ty * 32 - 2 + r, gx = tx * 32 - 2 + c;
      float v = (gy >= 0 && gy < 128 && gx >= 0 && gx < 128) ? img[gy * 128 + gx] : 0.f;
      lds[T1OFF + r * T1STR + c] = v;
    }
  }
  {
    const float* img = x2 + nb * 65536;
    for (int idx = tid; idx < 76 * 76; idx += 256) {
      int r = idx / 76, c = idx - r * 76;
      int gy = ty * 64 - 4 + r, gx = tx * 64 - 4 + c;
      float v = (gy >= 0 && gy < 256 && gx >= 0 && gx < 256) ? img[gy * 256 + gx] : 0.f;
      lds[T2OFF + r * T2STR + c] = v;
    }
  }
  __syncthreads();

  // per-lane (per-pixel) window base offsets in LDS
  const int pb0 = T0OFF + pr * T0STR + pc;            // layer0: stride 1, pad 1, k 3x3
  const int pb1 = T1OFF + (2 * pr) * T1STR + 2 * pc;  // layer1: stride 2, pad 2, k 6x6
  const int pb2 = T2OFF + (4 * pr) * T2STR + 4 * pc;  // layer2: stride 4, pad 4, k 12x12

  float acc[64];
  #pragma unroll
  for (int n = 0; n < 64; ++n) acc[n] = 0.f;

  // ---- K-loop: f32 FMA, W rows at wave-uniform address (-> s_load) ----
  #pragma unroll 1
  for (int ki = 0; ki < 3; ++ki) {
    #pragma unroll 1
    for (int kj = 0; kj < 3; ++kj) {
      const float a = lds[pb0 + ki * T0STR + kj];
      const float* __restrict__ wr = W + (ki * 3 + kj) * 64;
      #pragma unroll
      for (int n = 0; n < 64; ++n) acc[n] = fmaf(a, wr[n], acc[n]);
    }
  }
  #pragma unroll 1
  for (int ki = 0; ki < 6; ++ki) {
    #pragma unroll 1
    for (int kj = 0; kj < 6; ++kj) {
      const float a = lds[pb1 + ki * T1STR + kj];
      const float* __restrict__ wr = W + (9 + ki * 6 + kj) * 64;
      #pragma unroll
      for (int n = 0; n < 64; ++n) acc[n] = fmaf(a, wr[n], acc[n]);
    }
  }
  #pragma unroll 1
  for (int ki = 0; ki < 12; ++ki) {
    #pragma unroll 1
    for (int kj = 0; kj < 12; ++kj) {
      const float a = lds[pb2 + ki * T2STR + kj];
      const float* __restrict__ wr = W + (45 + ki * 12 + kj) * 64;
      #pragma unroll
      for (int n = 0; n < 64; ++n) acc[n] = fmaf(a, wr[n], acc[n]);
    }
  }

  // ---- epilogue (all per-lane, f32): ReLU -> softmax(64) -> scale -> store ----
  float m = 0.f;
  #pragma unroll
  for (int n = 0; n < 64; ++n) {
    acc[n] = fmaxf(acc[n], 0.f);
    m = fmaxf(m, acc[n]);
  }
  float ssum = 0.f;
  #pragma unroll
  for (int n = 0; n < 64; ++n) {
    float e = exp2f((acc[n] - m) * 1.4426950408889634f);
    acc[n] = e;
    ssum += e;
  }

  const int gy = ty * 16 + pr;
  const int gx = tx * 16 + pc;
  const float sc = x0[nb * 4096 + gy * 64 + gx] / ssum;

  // out[nb, 0, gy*8 + a, gx*8 + b], value index n = a*8 + b
  float* op = out + nb * 262144 + (gy * 8) * 512 + gx * 8;
  #pragma unroll
  for (int a = 0; a < 8; ++a) {
    float4 v0 = make_float4(acc[a * 8 + 0] * sc, acc[a * 8 + 1] * sc,
                            acc[a * 8 + 2] * sc, acc[a * 8 + 3] * sc);
    float4 v1 = make_float4(acc[a * 8 + 4] * sc, acc[a * 8 + 5] * sc,
                            acc[a * 8 + 6] * sc, acc[a * 8 + 7] * sc);
    *(float4*)(op + a * 512)     = v0;
    *(float4*)(op + a * 512 + 4) = v1;
  }
}

extern "C" void kernel_launch(void* const* d_in, const int* in_sizes, int n_in,
                              void* d_out, int out_size, void* d_ws, size_t ws_size,
                              hipStream_t stream) {
  const float* x0 = (const float*)d_in[0];
  const float* x1 = (const float*)d_in[1];
  const float* x2 = (const float*)d_in[2];
  const float* W  = (const float*)d_in[3];
  float* outp     = (float*)d_out;
  fuse_kernel<<<dim3(1024), dim3(256), 0, stream>>>(x0, x1, x2, W, outp);
}

// Round 3
// 154.992 us; speedup vs baseline: 1.0360x; 1.0360x over previous
//
#include <hip/hip_runtime.h>

typedef _Float16 f16;
typedef f16 f16x8 __attribute__((ext_vector_type(8)));
typedef f16 f16x4 __attribute__((ext_vector_type(4)));
typedef float f32x4 __attribute__((ext_vector_type(4)));

// ---- LDS tile strides/offsets (units: f16 elements) ----
#define S0 20
#define S1 40
#define S2 84
#define T0OFF 0
#define T1OFF 380            // 19*20
#define T2OFF 1820           // 380 + 36*40
#define TILE_HALVES 8208     // 1820 + 76*84 = 8204, padded to 16B
#define SCRSTR 68            // scratch row stride (floats), 64 + 4 pad
#define LOG2E 1.4426950408889634f

// K' = 256 layout (8 ksteps of 32):
//  kp in [0,16)   : layer0, ki=kp>>2, kj=kp&3   ; real iff ki<3 && kj<3 -> orig = 3*ki+kj
//  kp in [16,64)  : layer1, kk=kp-16, ki=kk>>3, kj=kk&7 ; real iff kj<6 -> orig = 9+6*ki+kj
//  kp in [64,256) : layer2, kk=kp-64, ki=kk>>4, kj=kk&15; real iff kj<12 -> orig = 45+12*ki+kj
__global__ void prep_wt(const float* __restrict__ W, f16* __restrict__ Wt) {
  const int n  = blockIdx.x;    // 0..63
  const int kp = threadIdx.x;   // 0..255
  int orig = -1;
  if (kp < 16)      { int ki = kp >> 2, kj = kp & 3;                  if (ki < 3 && kj < 3) orig = 3*ki + kj; }
  else if (kp < 64) { int kk = kp - 16; int ki = kk >> 3, kj = kk & 7; if (kj < 6)          orig = 9 + 6*ki + kj; }
  else              { int kk = kp - 64; int ki = kk >> 4, kj = kk & 15; if (kj < 12)        orig = 45 + 12*ki + kj; }
  float v = (orig >= 0) ? W[orig * 64 + n] : 0.f;
  Wt[n * 256 + kp] = (f16)v;
}

__global__ __launch_bounds__(256, 3) void fuse_kernel(
    const float* __restrict__ x0, const float* __restrict__ x1,
    const float* __restrict__ x2, const f16* __restrict__ Wt,
    float* __restrict__ out)
{
  __shared__ f16   tiles[TILE_HALVES];
  __shared__ float scratch[4 * 16 * SCRSTR];   // 4 waves x 16 px x 68

  const int tid  = threadIdx.x;
  const int bid  = blockIdx.x;
  const int nb   = bid >> 4;          // image
  const int ty   = (bid >> 2) & 3;    // 16-px tile row
  const int tx   = bid & 3;           // 16-px tile col
  const int lane = tid & 63;
  const int wid  = tid >> 6;
  const int ln   = lane & 15;
  const int quad = lane >> 4;

  // ---- stage FULL strided footprints to LDS (every slot written -> deterministic) ----
  {
    const float* img = x0 + nb * 4096;
    for (int idx = tid; idx < 19 * 20; idx += 256) {
      int r = idx / 20, c = idx - r * 20;
      int gy = ty * 16 - 1 + r, gx = tx * 16 - 1 + c;
      float v = ((unsigned)gy < 64u && (unsigned)gx < 64u) ? img[gy * 64 + gx] : 0.f;
      tiles[T0OFF + r * S0 + c] = (f16)v;
    }
  }
  {
    const float* img = x1 + nb * 16384;
    for (int idx = tid; idx < 36 * 40; idx += 256) {
      int r = idx / 40, c = idx - r * 40;
      int gy = ty * 32 - 2 + r, gx = tx * 32 - 2 + c;
      float v = ((unsigned)gy < 128u && (unsigned)gx < 128u) ? img[gy * 128 + gx] : 0.f;
      tiles[T1OFF + r * S1 + c] = (f16)v;
    }
  }
  {
    const float* img = x2 + nb * 65536;
    for (int idx = tid; idx < 76 * 84; idx += 256) {
      int r = idx / 84, c = idx - r * 84;
      int gy = ty * 64 - 4 + r, gx = tx * 64 - 4 + c;
      float v = ((unsigned)gy < 256u && (unsigned)gx < 256u) ? img[gy * 256 + gx] : 0.f;
      tiles[T2OFF + r * S2 + c] = (f16)v;
    }
  }
  __syncthreads();

  f32x4 acc[4][4];   // [chunk cc][t]; D row = pixel col (quad*4+r), D col n = 16t+ln
  #pragma unroll
  for (int c = 0; c < 4; ++c)
    #pragma unroll
    for (int t = 0; t < 4; ++t)
      acc[c][t] = (f32x4){0.f, 0.f, 0.f, 0.f};

  const int dj = (quad < 2) ? (S0 - 4) : 0;   // l0 second-row jump for kstep0

  // ---- kstep 0: quads 0,1 -> layer0 ; quads 2,3 -> layer1 (scalar u16 gathers) ----
  {
    const f16x8* bp0 = (const f16x8*)(Wt + (ln)*256 + quad*8);
    f16x8 bf[4];
    #pragma unroll
    for (int t = 0; t < 4; ++t) bf[t] = bp0[t*16*(256/8)];   // (t*16+ln)*256 ; 256/8 f16x8 per row
    #pragma unroll
    for (int cc = 0; cc < 4; ++cc) {
      const int py = wid * 4 + cc;
      const int base_l0 = T0OFF + (py + 2*quad) * S0 + ln;
      const int base_l1 = T1OFF + (2*py + quad - 2) * S1 + 2*ln;
      const int a0 = (quad < 2) ? base_l0 : base_l1;
      const int a1 = a0 + dj;
      f16x8 a;
      #pragma unroll
      for (int j = 0; j < 4; ++j) a[j] = tiles[a0 + j];
      #pragma unroll
      for (int j = 4; j < 8; ++j) a[j] = tiles[a1 + j];
      #pragma unroll
      for (int t = 0; t < 4; ++t)
        acc[cc][t] = __builtin_amdgcn_mfma_f32_16x16x32_f16(a, bf[t], acc[cc][t], 0, 0, 0);
    }
  }
  // ---- kstep 1: all layer1, row ki = 2+quad ----
  {
    f16x8 bf[4];
    #pragma unroll
    for (int t = 0; t < 4; ++t)
      bf[t] = *(const f16x8*)(Wt + (t*16 + ln)*256 + 32 + quad*8);
    #pragma unroll
    for (int cc = 0; cc < 4; ++cc) {
      const int py = wid * 4 + cc;
      const int b1 = T1OFF + (2*py + 2 + quad) * S1 + 2*ln;
      f16x8 a;
      #pragma unroll
      for (int j = 0; j < 8; ++j) a[j] = tiles[b1 + j];
      #pragma unroll
      for (int t = 0; t < 4; ++t)
        acc[cc][t] = __builtin_amdgcn_mfma_f32_16x16x32_f16(a, bf[t], acc[cc][t], 0, 0, 0);
    }
  }
  // ---- ksteps 2..7: layer2, vector b64 gathers ----
  #pragma unroll 1
  for (int s = 2; s < 8; ++s) {
    f16x8 bf[4];
    #pragma unroll
    for (int t = 0; t < 4; ++t)
      bf[t] = *(const f16x8*)(Wt + (t*16 + ln)*256 + s*32 + quad*8);
    #pragma unroll
    for (int cc = 0; cc < 4; ++cc) {
      const int py = wid * 4 + cc;
      const int b2 = T2OFF + (4*py + 2*(s - 2) + (quad >> 1)) * S2 + 4*ln + 8*(quad & 1);
      f16x4 lo = *(const f16x4*)&tiles[b2];
      f16x4 hi = *(const f16x4*)&tiles[b2 + 4];
      f16x8 a;
      a[0] = lo[0]; a[1] = lo[1]; a[2] = lo[2]; a[3] = lo[3];
      a[4] = hi[0]; a[5] = hi[1]; a[6] = hi[2]; a[7] = hi[3];
      #pragma unroll
      for (int t = 0; t < 4; ++t)
        acc[cc][t] = __builtin_amdgcn_mfma_f32_16x16x32_f16(a, bf[t], acc[cc][t], 0, 0, 0);
    }
  }

  // ---- epilogue per chunk: LDS transpose -> per-lane softmax -> coalesced stores ----
  float* swp = scratch + wid * 16 * SCRSTR;
  #pragma unroll 1
  for (int cc = 0; cc < 4; ++cc) {
    const int py = wid * 4 + cc;
    // transpose: slot [pixel-col][n]
    #pragma unroll
    for (int t = 0; t < 4; ++t)
      #pragma unroll
      for (int r = 0; r < 4; ++r)
        swp[(quad * 4 + r) * SCRSTR + t * 16 + ln] = fmaxf(acc[cc][t][r], 0.f);
    asm volatile("s_waitcnt lgkmcnt(0)" ::: "memory");

    // lane owns pixel col px=ln, n-quarter q=quad
    f32x4 v[4];
    #pragma unroll
    for (int u = 0; u < 4; ++u)
      v[u] = *(const f32x4*)&swp[ln * SCRSTR + quad * 16 + 4 * u];
    asm volatile("s_waitcnt lgkmcnt(0)" ::: "memory");

    float m = 0.f;
    #pragma unroll
    for (int u = 0; u < 4; ++u)
      #pragma unroll
      for (int e = 0; e < 4; ++e) m = fmaxf(m, v[u][e]);
    m = fmaxf(m, __shfl_xor(m, 16));
    m = fmaxf(m, __shfl_xor(m, 32));
    float ssum = 0.f;
    #pragma unroll
    for (int u = 0; u < 4; ++u)
      #pragma unroll
      for (int e = 0; e < 4; ++e) {
        float x = exp2f((v[u][e] - m) * LOG2E);
        v[u][e] = x;
        ssum += x;
      }
    ssum += __shfl_xor(ssum, 16);
    ssum += __shfl_xor(ssum, 32);

    const int gy = ty * 16 + py;
    const int gx = tx * 16 + ln;
    const float sc = x0[nb * 4096 + gy * 64 + gx] / ssum;   // exact f32 x0

    float* op = out + nb * 262144 + (gy * 8 + 2 * quad) * 512 + gx * 8;
    *(f32x4*)(op)             = v[0] * sc;
    *(f32x4*)(op + 4)         = v[1] * sc;
    *(f32x4*)(op + 512)       = v[2] * sc;
    *(f32x4*)(op + 512 + 4)   = v[3] * sc;
  }
}

extern "C" void kernel_launch(void* const* d_in, const int* in_sizes, int n_in,
                              void* d_out, int out_size, void* d_ws, size_t ws_size,
                              hipStream_t stream) {
  const float* x0 = (const float*)d_in[0];
  const float* x1 = (const float*)d_in[1];
  const float* x2 = (const float*)d_in[2];
  const float* W  = (const float*)d_in[3];
  float* outp     = (float*)d_out;
  f16* Wt         = (f16*)d_ws;   // 64*256 f16 = 32 KB

  prep_wt<<<dim3(64), dim3(256), 0, stream>>>(W, Wt);
  fuse_kernel<<<dim3(1024), dim3(256), 0, stream>>>(x0, x1, x2, Wt, outp);
}

// Round 4
// 140.862 us; speedup vs baseline: 1.1400x; 1.1003x over previous
//
#include <hip/hip_runtime.h>

typedef _Float16 f16;
typedef f16 f16x8 __attribute__((ext_vector_type(8)));
typedef f16 f16x4 __attribute__((ext_vector_type(4)));
typedef float f32x4 __attribute__((ext_vector_type(4)));

// ---- LDS tile strides/offsets (units: f16 elements) ----
// x0: 19 rows x 24 cols (gx in [tx*16-4,  tx*16+20)), stride 28
// x1: 36 rows x 44 cols (gx in [tx*32-4,  tx*32+40)), stride 48
// x2: 76 rows x 88 cols (gx in [tx*64-8,  tx*64+80)), stride 92
#define S0 28
#define S1 48
#define S2 92
#define T0OFF 0
#define T1OFF (19 * S0)                 // 532
#define T2OFF (T1OFF + 36 * S1)         // 2260
#define TILEH (T2OFF + 76 * S2)         // 9252 f16 = 18504 B
#define SCRSTR 68
#define LOG2E 1.4426950408889634f

// K' = 256 layout (8 ksteps of 32):
//  kp in [0,16)   : layer0, ki=kp>>2, kj=kp&3   ; real iff ki<3 && kj<3 -> orig = 3*ki+kj
//  kp in [16,64)  : layer1, kk=kp-16, ki=kk>>3, kj=kk&7 ; real iff kj<6 -> orig = 9+6*ki+kj
//  kp in [64,256) : layer2, kk=kp-64, ki=kk>>4, kj=kk&15; real iff kj<12 -> orig = 45+12*ki+kj
__global__ void prep_wt(const float* __restrict__ W, f16* __restrict__ Wt) {
  const int n  = blockIdx.x;    // 0..63
  const int kp = threadIdx.x;   // 0..255
  int orig = -1;
  if (kp < 16)      { int ki = kp >> 2, kj = kp & 3;                  if (ki < 3 && kj < 3) orig = 3*ki + kj; }
  else if (kp < 64) { int kk = kp - 16; int ki = kk >> 3, kj = kk & 7; if (kj < 6)          orig = 9 + 6*ki + kj; }
  else              { int kk = kp - 64; int ki = kk >> 4, kj = kk & 15; if (kj < 12)        orig = 45 + 12*ki + kj; }
  float v = (orig >= 0) ? W[orig * 64 + n] : 0.f;
  Wt[n * 256 + kp] = (f16)v;
}

__global__ __launch_bounds__(256, 3) void fuse_kernel(
    const float* __restrict__ x0, const float* __restrict__ x1,
    const float* __restrict__ x2, const f16* __restrict__ Wt,
    float* __restrict__ out)
{
  __shared__ f16   tiles[TILEH];
  __shared__ float scratch[4 * 16 * SCRSTR];

  const int tid  = threadIdx.x;
  const int bid  = blockIdx.x;
  const int nb   = bid >> 4;          // image
  const int ty   = (bid >> 2) & 3;    // 16-px tile row
  const int tx   = bid & 3;           // 16-px tile col
  const int lane = tid & 63;
  const int wid  = tid >> 6;
  const int ln   = lane & 15;
  const int quad = lane >> 4;

  // ================= issue x2 loads FIRST (biggest input, longest latency) ==
  // 76 rows x 22 float4 = 1672 items
  f32x4 v2[7];
  int   off2[7];
  bool  ok2[7];
  {
    const float* img = x2 + nb * 65536;
    #pragma unroll
    for (int i = 0; i < 7; ++i) {
      int idx = tid + 256 * i;
      int r  = idx / 22, c4 = idx - r * 22;
      int gy = ty * 64 - 4 + r;
      int gx = tx * 64 - 8 + 4 * c4;
      bool inb = (idx < 1672) && ((unsigned)gy < 256u) && ((unsigned)gx < 256u);
      v2[i]  = inb ? *(const f32x4*)(img + gy * 256 + gx) : (f32x4){0.f, 0.f, 0.f, 0.f};
      off2[i] = T2OFF + r * S2 + 4 * c4;
      ok2[i]  = (idx < 1672);
    }
  }

  // ================= stage x1 (36 x 11 float4 = 396) and x0 (19 x 6 = 114) ==
  {
    const float* img = x1 + nb * 16384;
    #pragma unroll
    for (int i = 0; i < 2; ++i) {
      int idx = tid + 256 * i;
      int r  = idx / 11, c4 = idx - r * 11;
      int gy = ty * 32 - 2 + r;
      int gx = tx * 32 - 4 + 4 * c4;
      bool inb = (idx < 396) && ((unsigned)gy < 128u) && ((unsigned)gx < 128u);
      f32x4 t = inb ? *(const f32x4*)(img + gy * 128 + gx) : (f32x4){0.f, 0.f, 0.f, 0.f};
      if (idx < 396) {
        f16x4 h; h[0] = (f16)t[0]; h[1] = (f16)t[1]; h[2] = (f16)t[2]; h[3] = (f16)t[3];
        *(f16x4*)&tiles[T1OFF + r * S1 + 4 * c4] = h;
      }
    }
  }
  {
    const float* img = x0 + nb * 4096;
    int idx = tid;
    int r  = idx / 6, c4 = idx - r * 6;
    int gy = ty * 16 - 1 + r;
    int gx = tx * 16 - 4 + 4 * c4;
    bool inb = (idx < 114) && ((unsigned)gy < 64u) && ((unsigned)gx < 64u);
    f32x4 t = inb ? *(const f32x4*)(img + gy * 64 + gx) : (f32x4){0.f, 0.f, 0.f, 0.f};
    if (idx < 114) {
      f16x4 h; h[0] = (f16)t[0]; h[1] = (f16)t[1]; h[2] = (f16)t[2]; h[3] = (f16)t[3];
      *(f16x4*)&tiles[T0OFF + r * S0 + 4 * c4] = h;
    }
  }
  __syncthreads();   // x0/x1 tiles ready (x2 loads still possibly in flight)

  f32x4 acc[4][4];
  #pragma unroll
  for (int c = 0; c < 4; ++c)
    #pragma unroll
    for (int t = 0; t < 4; ++t)
      acc[c][t] = (f32x4){0.f, 0.f, 0.f, 0.f};

  // ---- kstep 0: quads 0,1 -> layer0 ; quads 2,3 -> layer1 ----
  {
    f16x8 bf[4];
    #pragma unroll
    for (int t = 0; t < 4; ++t)
      bf[t] = *(const f16x8*)(Wt + (t * 16 + ln) * 256 + quad * 8);
    #pragma unroll
    for (int cc = 0; cc < 4; ++cc) {
      const int py = wid * 4 + cc;
      f16x8 a;
      if (quad < 2) {
        // layer0: ki = 2*quad + (j>>2), kj = j&3; row = py+ki, col = ln+3+kj
        const int a0 = T0OFF + (py + 2 * quad) * S0 + ln + 3;
        #pragma unroll
        for (int j = 0; j < 4; ++j) a[j]     = tiles[a0 + j];
        #pragma unroll
        for (int j = 0; j < 4; ++j) a[4 + j] = tiles[a0 + S0 + j];
      } else {
        // layer1: ki = quad-2, kj = j; row = 2py+ki, col = 2ln+2+kj
        const int a1 = T1OFF + (2 * py + quad - 2) * S1 + 2 * ln + 2;
        #pragma unroll
        for (int j = 0; j < 8; ++j) a[j] = tiles[a1 + j];
      }
      #pragma unroll
      for (int t = 0; t < 4; ++t)
        acc[cc][t] = __builtin_amdgcn_mfma_f32_16x16x32_f16(a, bf[t], acc[cc][t], 0, 0, 0);
    }
  }
  // ---- kstep 1: all layer1, ki = 2+quad ----
  {
    f16x8 bf[4];
    #pragma unroll
    for (int t = 0; t < 4; ++t)
      bf[t] = *(const f16x8*)(Wt + (t * 16 + ln) * 256 + 32 + quad * 8);
    #pragma unroll
    for (int cc = 0; cc < 4; ++cc) {
      const int py = wid * 4 + cc;
      const int a1 = T1OFF + (2 * py + 2 + quad) * S1 + 2 * ln + 2;
      f16x8 a;
      #pragma unroll
      for (int j = 0; j < 8; ++j) a[j] = tiles[a1 + j];
      #pragma unroll
      for (int t = 0; t < 4; ++t)
        acc[cc][t] = __builtin_amdgcn_mfma_f32_16x16x32_f16(a, bf[t], acc[cc][t], 0, 0, 0);
    }
  }

  // ---- now store x2 tile to LDS (loads have had max time to arrive) ----
  #pragma unroll
  for (int i = 0; i < 7; ++i) {
    if (ok2[i]) {
      f16x4 h0; h0[0] = (f16)v2[i][0]; h0[1] = (f16)v2[i][1];
      h0[2] = (f16)v2[i][2]; h0[3] = (f16)v2[i][3];
      *(f16x4*)&tiles[off2[i]] = h0;
    }
  }
  __syncthreads();   // x2 tile ready

  // ---- ksteps 2..7: layer2 ----
  // row = 4py + 2(s-2) + (quad>>1), col = 4ln + 4 + 8(quad&1) + j
  #pragma unroll 2
  for (int s = 2; s < 8; ++s) {
    f16x8 bf[4];
    #pragma unroll
    for (int t = 0; t < 4; ++t)
      bf[t] = *(const f16x8*)(Wt + (t * 16 + ln) * 256 + s * 32 + quad * 8);
    #pragma unroll
    for (int cc = 0; cc < 4; ++cc) {
      const int py = wid * 4 + cc;
      const int b2 = T2OFF + (4 * py + 2 * (s - 2) + (quad >> 1)) * S2 + 4 * ln + 4 + 8 * (quad & 1);
      f16x4 lo = *(const f16x4*)&tiles[b2];
      f16x4 hi = *(const f16x4*)&tiles[b2 + 4];
      f16x8 a;
      a[0] = lo[0]; a[1] = lo[1]; a[2] = lo[2]; a[3] = lo[3];
      a[4] = hi[0]; a[5] = hi[1]; a[6] = hi[2]; a[7] = hi[3];
      #pragma unroll
      for (int t = 0; t < 4; ++t)
        acc[cc][t] = __builtin_amdgcn_mfma_f32_16x16x32_f16(a, bf[t], acc[cc][t], 0, 0, 0);
    }
  }

  // ---- epilogue per chunk: LDS transpose -> per-lane softmax -> coalesced stores ----
  float* swp = scratch + wid * 16 * SCRSTR;
  #pragma unroll 1
  for (int cc = 0; cc < 4; ++cc) {
    const int py = wid * 4 + cc;
    #pragma unroll
    for (int t = 0; t < 4; ++t)
      #pragma unroll
      for (int r = 0; r < 4; ++r)
        swp[(quad * 4 + r) * SCRSTR + t * 16 + ln] = fmaxf(acc[cc][t][r], 0.f);
    asm volatile("s_waitcnt lgkmcnt(0)" ::: "memory");

    f32x4 v[4];
    #pragma unroll
    for (int u = 0; u < 4; ++u)
      v[u] = *(const f32x4*)&swp[ln * SCRSTR + quad * 16 + 4 * u];
    asm volatile("s_waitcnt lgkmcnt(0)" ::: "memory");

    float m = 0.f;
    #pragma unroll
    for (int u = 0; u < 4; ++u)
      #pragma unroll
      for (int e = 0; e < 4; ++e) m = fmaxf(m, v[u][e]);
    m = fmaxf(m, __shfl_xor(m, 16));
    m = fmaxf(m, __shfl_xor(m, 32));
    float ssum = 0.f;
    #pragma unroll
    for (int u = 0; u < 4; ++u)
      #pragma unroll
      for (int e = 0; e < 4; ++e) {
        float x = exp2f((v[u][e] - m) * LOG2E);
        v[u][e] = x;
        ssum += x;
      }
    ssum += __shfl_xor(ssum, 16);
    ssum += __shfl_xor(ssum, 32);

    const int gy = ty * 16 + py;
    const int gx = tx * 16 + ln;
    const float sc = x0[nb * 4096 + gy * 64 + gx] / ssum;   // exact f32 x0

    float* op = out + nb * 262144 + (gy * 8 + 2 * quad) * 512 + gx * 8;
    *(f32x4*)(op)           = v[0] * sc;
    *(f32x4*)(op + 4)       = v[1] * sc;
    *(f32x4*)(op + 512)     = v[2] * sc;
    *(f32x4*)(op + 512 + 4) = v[3] * sc;
  }
}

extern "C" void kernel_launch(void* const* d_in, const int* in_sizes, int n_in,
                              void* d_out, int out_size, void* d_ws, size_t ws_size,
                              hipStream_t stream) {
  const float* x0 = (const float*)d_in[0];
  const float* x1 = (const float*)d_in[1];
  const float* x2 = (const float*)d_in[2];
  const float* W  = (const float*)d_in[3];
  float* outp     = (float*)d_out;
  f16* Wt         = (f16*)d_ws;   // 64*256 f16 = 32 KB

  prep_wt<<<dim3(64), dim3(256), 0, stream>>>(W, Wt);
  fuse_kernel<<<dim3(1024), dim3(256), 0, stream>>>(x0, x1, x2, Wt, outp);
}